// Round 4
// baseline (338.780 us; speedup 1.0000x reference)
//
#include <hip/hip_runtime.h>

#define IN_H  224
#define IN_W  224
#define OUT_H 218
#define OUT_W 218
#define NCH   64
#define KSZ   7
#define WPAD  52     // padded per-channel weight count (13 x float4)
#define CHUNK 32     // output x-positions per wave
#define LROW  36     // LDS row stride in floats (16B-aligned rows)

// Repack weights [64][49] -> [64][52] (zero-padded) into d_ws so each lane
// can load its channel's weights as 13 x dwordx4.
__global__ __launch_bounds__(256) void repack_w(const float* __restrict__ wgt,
                                                float* __restrict__ wr) {
    int i = blockIdx.x * 256 + threadIdx.x;
    if (i < NCH * WPAD) {
        int c = i / WPAD, k = i - c * WPAD;
        wr[i] = (k < KSZ * KSZ) ? wgt[c * KSZ * KSZ + k] : 0.f;
    }
}

// Channel-per-lane conv: lane = output channel. Weights live in VGPRs for the
// whole kernel (loaded once). The 7-row input window is lane-uniform
// (broadcast loads) and shared by all 64 channels. Outputs bounce through a
// wave-private LDS tile for coalesced stores.
// Block = 4 waves; wave w handles output row blockIdx.y*4+w, x-chunk of 32.
__global__ __launch_bounds__(256) void conv7x7_cpl(
    const float* __restrict__ in,
    const float* __restrict__ wr,
    float* __restrict__ out)
{
    __shared__ float lds[4 * NCH * LROW];  // 36864 B

    const int lane = threadIdx.x & 63;   // output channel
    const int wid  = threadIdx.x >> 6;   // wave id
    const int n    = blockIdx.z;
    const int X0   = blockIdx.x * CHUNK;
    const int oy   = blockIdx.y * 4 + wid;
    const int oyl  = min(oy, OUT_H - 1); // clamped row for loads (219->217)

    float* wlds = &lds[wid * NCH * LROW];

    // ---- per-lane (per-channel) weights: 13 x dwordx4, once per wave ----
    float w[WPAD];
    {
        const float4* wb = reinterpret_cast<const float4*>(wr + lane * WPAD);
#pragma unroll
        for (int k = 0; k < 13; ++k) {
            float4 v = wb[k];
            w[4 * k]     = v.x;
            w[4 * k + 1] = v.y;
            w[4 * k + 2] = v.z;
            w[4 * k + 3] = v.w;
        }
    }

    const float* inb = in + (size_t)n * (IN_H * IN_W) + (size_t)oyl * IN_W;

    // ---- compute: 8 groups x 4 x-steps; window reloaded per group ----
    for (int g = 0; g < 8; ++g) {
        const int b  = X0 + 4 * g;            // <= 220, 16B-aligned
        const int a1 = min(b + 4, IN_W - 4);  // clamp: clamped slots are only
        const int a2 = min(b + 8, IN_W - 4);  // read by masked-off steps
        float win[KSZ][12];
#pragma unroll
        for (int r = 0; r < KSZ; ++r) {
            const float* rp = inb + r * IN_W;
            float4 A = *reinterpret_cast<const float4*>(rp + b);
            float4 B = *reinterpret_cast<const float4*>(rp + a1);
            float4 C = *reinterpret_cast<const float4*>(rp + a2);
            win[r][0] = A.x; win[r][1] = A.y; win[r][2]  = A.z; win[r][3]  = A.w;
            win[r][4] = B.x; win[r][5] = B.y; win[r][6]  = B.z; win[r][7]  = B.w;
            win[r][8] = C.x; win[r][9] = C.y; win[r][10] = C.z; win[r][11] = C.w;
        }
#pragma unroll
        for (int st = 0; st < 4; ++st) {
            float acc = 0.f;
#pragma unroll
            for (int r = 0; r < KSZ; ++r)
#pragma unroll
                for (int s = 0; s < KSZ; ++s)
                    acc = fmaf(win[r][s + st], w[r * KSZ + s], acc);
            wlds[lane * LROW + 4 * g + st] = acc;  // bank = (4*lane+x)%32, 8-way but 1 op/step
        }
    }

    // ---- store: LDS transpose -> coalesced global (2x128B per instr) ----
    const int c0  = lane >> 5;   // 0/1
    const int col = lane & 31;
    const bool cv = (X0 + col < OUT_W) && (oy < OUT_H);
    const size_t plane = (size_t)OUT_H * OUT_W;
    float* op = out + (size_t)n * NCH * plane + (size_t)oy * OUT_W + X0 + col
                    + (size_t)c0 * plane;
#pragma unroll 4
    for (int j = 0; j < 32; ++j) {
        float v = wlds[(2 * j + c0) * LROW + col];
        if (cv) *op = v;
        op += 2 * plane;
    }
}

extern "C" void kernel_launch(void* const* d_in, const int* in_sizes, int n_in,
                              void* d_out, int out_size, void* d_ws, size_t ws_size,
                              hipStream_t stream) {
    const float* in  = (const float*)d_in[0];
    const float* wgt = (const float*)d_in[1];
    float* out = (float*)d_out;
    float* wr  = (float*)d_ws;   // 64*52*4 = 13312 B

    repack_w<<<(NCH * WPAD + 255) / 256, 256, 0, stream>>>(wgt, wr);

    dim3 grid((OUT_W + CHUNK - 1) / CHUNK, (OUT_H + 3) / 4, 32);
    conv7x7_cpl<<<grid, 256, 0, stream>>>(in, wr, out);
}

// Round 5
// 200.433 us; speedup vs baseline: 1.6902x; 1.6902x over previous
//
#include <hip/hip_runtime.h>

#define IN_H  224
#define IN_W  224
#define OUT_H 218
#define OUT_W 218
#define NCH   64
#define PLANE (OUT_H * OUT_W)
#define TSTR  232   // LDS row stride in floats: 232%32=8 -> dy-groups spread banks

typedef short bf16x8 __attribute__((ext_vector_type(8)));
typedef float f32x4  __attribute__((ext_vector_type(4)));

__device__ inline unsigned short f2bf(float f) {   // RNE f32 -> bf16
    unsigned int u = __builtin_bit_cast(unsigned int, f);
    u = (u + 0x7fffu + ((u >> 16) & 1u)) >> 16;
    return (unsigned short)u;
}

// Pack weights into ready-made MFMA A-fragments (bf16, 7x7 zero-padded to 8x8).
// d_ws layout: [fc = mt*2+kt][lane][4 x u32]; ch = 16*mt + (lane&15),
// dy = 4*kt + (lane>>4), word j = {dx=2j (lo), dx=2j+1 (hi)}.
__global__ __launch_bounds__(512) void repack_w(const float* __restrict__ wgt,
                                                unsigned int* __restrict__ wa) {
    const int t    = threadIdx.x;
    const int lane = t & 63;
    const int fc   = t >> 6;              // 0..7
    const int mt   = fc >> 1, kt = fc & 1;
    const int ch   = 16 * mt + (lane & 15);
    const int dy   = 4 * kt + (lane >> 4);
    unsigned int w[4];
#pragma unroll
    for (int j = 0; j < 4; ++j) {
        float lo = (dy < 7 && 2 * j     < 7) ? wgt[ch * 49 + dy * 7 + 2 * j]     : 0.f;
        float hi = (dy < 7 && 2 * j + 1 < 7) ? wgt[ch * 49 + dy * 7 + 2 * j + 1] : 0.f;
        w[j] = (unsigned int)f2bf(lo) | ((unsigned int)f2bf(hi) << 16);
    }
    reinterpret_cast<uint4*>(wa)[fc * 64 + lane] = make_uint4(w[0], w[1], w[2], w[3]);
}

// One block = one (image n, output row y). 4 waves cover x in 64-wide strips,
// each strip = 4 n-groups of 16 consecutive pixels. K=64 (8x8 padded kernel),
// M=64 channels = 4 m-tiles, mfma_f32_16x16x32_bf16.
__global__ __launch_bounds__(256) void conv7x7_mfma(
    const float* __restrict__ in,
    const unsigned int* __restrict__ wa,
    float* __restrict__ out)
{
    __shared__ float tile[8 * TSTR];      // 7424 B

    const int tid  = threadIdx.x;
    const int lane = tid & 63;
    const int wid  = tid >> 6;
    const int g    = lane >> 4;           // k-group -> dy offset
    const int c    = lane & 15;           // pixel-in-group / channel-in-tile
    const int y    = blockIdx.x;
    const int n    = blockIdx.y;

    // ---- stationary A-fragments: 8 x dwordx4 ----
    union AB { uint4 u; bf16x8 v; };
    AB af[8];
    const uint4* wa4 = reinterpret_cast<const uint4*>(wa);
#pragma unroll
    for (int f = 0; f < 8; ++f) af[f].u = wa4[f * 64 + lane];

    // ---- stage 8 input rows (clamped; row 7 only meets zero weights) ----
    const float* inb = in + (size_t)n * (IN_H * IN_W);
    for (int idx = tid; idx < 8 * 112; idx += 256) {
        int r  = idx / 112, c2 = idx - r * 112;
        int iny = min(y + r, IN_H - 1);
        float2 v = *reinterpret_cast<const float2*>(inb + iny * IN_W + 2 * c2);
        tile[r * TSTR + 2 * c2]     = v.x;
        tile[r * TSTR + 2 * c2 + 1] = v.y;
    }
    if (tid < 64) tile[(tid >> 3) * TSTR + 224 + (tid & 7)] = 0.f;  // zero pad cols
    __syncthreads();

    const size_t obase = (size_t)n * NCH * PLANE + (size_t)y * OUT_W;
    const int x0w = 64 * wid;

    for (int q = 0; q < 4; ++q) {
        const int x0 = x0w + 16 * q;
        if (x0 >= OUT_W) break;           // wave-uniform

        // ---- B fragments: 8 consecutive f32 per lane -> 8 bf16 ----
        AB bf[2];
#pragma unroll
        for (int kt = 0; kt < 2; ++kt) {
            const float* rb = &tile[(4 * kt + g) * TSTR + x0 + c];
            unsigned int b0 = (unsigned int)f2bf(rb[0]) | ((unsigned int)f2bf(rb[1]) << 16);
            unsigned int b1 = (unsigned int)f2bf(rb[2]) | ((unsigned int)f2bf(rb[3]) << 16);
            unsigned int b2 = (unsigned int)f2bf(rb[4]) | ((unsigned int)f2bf(rb[5]) << 16);
            unsigned int b3 = (unsigned int)f2bf(rb[6]) | ((unsigned int)f2bf(rb[7]) << 16);
            bf[kt].u = make_uint4(b0, b1, b2, b3);
        }

        f32x4 acc[4] = {{0.f,0.f,0.f,0.f},{0.f,0.f,0.f,0.f},
                        {0.f,0.f,0.f,0.f},{0.f,0.f,0.f,0.f}};
#pragma unroll
        for (int mt = 0; mt < 4; ++mt) {
            acc[mt] = __builtin_amdgcn_mfma_f32_16x16x32_bf16(af[mt*2+0].v, bf[0].v, acc[mt], 0, 0, 0);
            acc[mt] = __builtin_amdgcn_mfma_f32_16x16x32_bf16(af[mt*2+1].v, bf[1].v, acc[mt], 0, 0, 0);
        }

        // ---- store: C col = pixel x0+c, row = 4g+r = channel-in-tile ----
        if (x0 + c < OUT_W) {
            float* op = out + obase + x0 + c + (size_t)(4 * g) * PLANE;
#pragma unroll
            for (int mt = 0; mt < 4; ++mt)
#pragma unroll
                for (int r = 0; r < 4; ++r)
                    op[(size_t)(16 * mt + r) * PLANE] = acc[mt][r];
        }
    }
}

extern "C" void kernel_launch(void* const* d_in, const int* in_sizes, int n_in,
                              void* d_out, int out_size, void* d_ws, size_t ws_size,
                              hipStream_t stream) {
    const float* in  = (const float*)d_in[0];
    const float* wgt = (const float*)d_in[1];
    float* out = (float*)d_out;
    unsigned int* wa = (unsigned int*)d_ws;   // 8*64*16 = 8192 B

    repack_w<<<1, 512, 0, stream>>>(wgt, wa);

    dim3 grid(OUT_H, 32);
    conv7x7_mfma<<<grid, 256, 0, stream>>>(in, wa, out);
}

// Round 6
// 174.855 us; speedup vs baseline: 1.9375x; 1.1463x over previous
//
#include <hip/hip_runtime.h>

#define IN_H  224
#define IN_W  224
#define OUT_H 218
#define OUT_W 218
#define NCH   64
#define PLANE (OUT_H * OUT_W)
#define TSTR  232    // LDS row stride (floats); 232%32=8 spreads dy-groups across banks
#define YB    8      // output rows per block (1 per wave)
#define NYB   28     // y-blocks: 28*8=224 rows, 218 valid
#define NBLK  (32 * NYB)   // 896 = 8 XCDs * 112 exactly -> bijective chunk map

typedef short bf16x8 __attribute__((ext_vector_type(8)));
typedef float f32x4  __attribute__((ext_vector_type(4)));

__device__ inline unsigned int f2bf(float f) {   // RNE f32 -> bf16 (proven R5)
    unsigned int u = __builtin_bit_cast(unsigned int, f);
    return (u + 0x7fffu + ((u >> 16) & 1u)) >> 16;
}

// Pack weights into ready-made MFMA A-fragments (bf16, 7x7 zero-padded to 8x8).
// [fc = mt*2+kt][lane]: ch = 16*mt + (lane&15), dy = 4*kt + (lane>>4),
// word j = {dx=2j (lo), dx=2j+1 (hi)}.   (verified in R5)
__global__ __launch_bounds__(512) void repack_w(const float* __restrict__ wgt,
                                                unsigned int* __restrict__ wa) {
    const int t    = threadIdx.x;
    const int lane = t & 63;
    const int fc   = t >> 6;
    const int mt   = fc >> 1, kt = fc & 1;
    const int ch   = 16 * mt + (lane & 15);
    const int dy   = 4 * kt + (lane >> 4);
    unsigned int w[4];
#pragma unroll
    for (int j = 0; j < 4; ++j) {
        float lo = (dy < 7 && 2 * j     < 7) ? wgt[ch * 49 + dy * 7 + 2 * j]     : 0.f;
        float hi = (dy < 7 && 2 * j + 1 < 7) ? wgt[ch * 49 + dy * 7 + 2 * j + 1] : 0.f;
        w[j] = f2bf(lo) | (f2bf(hi) << 16);
    }
    reinterpret_cast<uint4*>(wa)[fc * 64 + lane] = make_uint4(w[0], w[1], w[2], w[3]);
}

// Block = (n, 8 consecutive output rows), 8 waves, wave w -> row y0+w over the
// full width (14 x-strips of 16). All 64 channels per block (4 m-tiles).
// Writes per block: 7KB contiguous per channel-plane; chunked XCD mapping
// gives each XCD a contiguous ~97MB output region (write-locality theory).
__global__ __launch_bounds__(512) void conv7x7_mfma(
    const float* __restrict__ in,
    const unsigned int* __restrict__ wa,
    float* __restrict__ out)
{
    __shared__ float tile[15 * TSTR];   // 13920 B: input rows y0..y0+14 (+pad cols)

    const int tid  = threadIdx.x;
    const int lane = tid & 63;
    const int wid  = tid >> 6;          // wave id -> row offset
    const int g    = lane >> 4;         // k-group -> dy offset / channel sub-row
    const int c    = lane & 15;         // pixel-in-group

    // Chunked XCD mapping: dispatch round-robins bid%8 across XCDs; give XCD x
    // the contiguous rank range [x*112, (x+1)*112) = 4 whole images.
    const int bid  = blockIdx.x;
    const int rank = (bid & 7) * (NBLK / 8) + (bid >> 3);
    const int n    = rank / NYB;
    const int yb   = rank - n * NYB;
    const int y0   = yb * YB;

    // ---- stationary A-fragments: 8 x dwordx4 ----
    union AB { uint4 u; bf16x8 v; };
    AB af[8];
    const uint4* wa4 = reinterpret_cast<const uint4*>(wa);
#pragma unroll
    for (int f = 0; f < 8; ++f) af[f].u = wa4[f * 64 + lane];

    // ---- stage 15 input rows (clamped; clamped rows feed only masked waves) ----
    const float* inb = in + (size_t)n * (IN_H * IN_W);
    for (int idx = tid; idx < 15 * 116; idx += 512) {
        int r = idx / 116, c2 = idx - r * 116;
        int iny = min(y0 + r, IN_H - 1);
        float2 v = (c2 < 112) ? *reinterpret_cast<const float2*>(inb + iny * IN_W + 2 * c2)
                              : make_float2(0.f, 0.f);   // zero pad cols 224..231
        tile[r * TSTR + 2 * c2]     = v.x;
        tile[r * TSTR + 2 * c2 + 1] = v.y;
    }
    __syncthreads();

    const int oy = y0 + wid;
    const bool row_ok = (oy < OUT_H);
    // lane base: channel 4g, row oy, col c
    float* ob = out + (size_t)n * NCH * PLANE + (size_t)(4 * g) * PLANE
                    + (size_t)oy * OUT_W + c;

    for (int q = 0; q < 14; ++q) {
        const int x0 = 16 * q;

        // ---- B fragments: 8 consecutive f32 per lane -> 8 bf16 ----
        AB bf[2];
#pragma unroll
        for (int kt = 0; kt < 2; ++kt) {
            const float* rb = &tile[(wid + 4 * kt + g) * TSTR + x0 + c];
            unsigned int b0 = f2bf(rb[0]) | (f2bf(rb[1]) << 16);
            unsigned int b1 = f2bf(rb[2]) | (f2bf(rb[3]) << 16);
            unsigned int b2 = f2bf(rb[4]) | (f2bf(rb[5]) << 16);
            unsigned int b3 = f2bf(rb[6]) | (f2bf(rb[7]) << 16);
            bf[kt].u = make_uint4(b0, b1, b2, b3);
        }

        f32x4 acc[4] = {{0.f,0.f,0.f,0.f},{0.f,0.f,0.f,0.f},
                        {0.f,0.f,0.f,0.f},{0.f,0.f,0.f,0.f}};
#pragma unroll
        for (int mt = 0; mt < 4; ++mt) {
            acc[mt] = __builtin_amdgcn_mfma_f32_16x16x32_bf16(af[mt*2+0].v, bf[0].v, acc[mt], 0, 0, 0);
            acc[mt] = __builtin_amdgcn_mfma_f32_16x16x32_bf16(af[mt*2+1].v, bf[1].v, acc[mt], 0, 0, 0);
        }

        // ---- store: channel = 16mt + 4g + r, col = x0 + c ----
        if (row_ok && (x0 + c < OUT_W)) {
            float* op = ob + x0;
#pragma unroll
            for (int mt = 0; mt < 4; ++mt)
#pragma unroll
                for (int r = 0; r < 4; ++r)
                    op[(size_t)(16 * mt + r) * PLANE] = acc[mt][r];
        }
    }
}

extern "C" void kernel_launch(void* const* d_in, const int* in_sizes, int n_in,
                              void* d_out, int out_size, void* d_ws, size_t ws_size,
                              hipStream_t stream) {
    const float* in  = (const float*)d_in[0];
    const float* wgt = (const float*)d_in[1];
    float* out = (float*)d_out;
    unsigned int* wa = (unsigned int*)d_ws;   // 8*64*16 = 8192 B

    repack_w<<<1, 512, 0, stream>>>(wgt, wa);
    conv7x7_mfma<<<NBLK, 512, 0, stream>>>(in, wa, out);
}

// Round 7
// 106.236 us; speedup vs baseline: 3.1889x; 1.6459x over previous
//
#include <hip/hip_runtime.h>

#define IN_H  224
#define IN_W  224
#define OUT_H 218
#define OUT_W 218
#define NCH   64
#define PLANE (OUT_H * OUT_W)
#define TSTR  232            // input tile row stride (floats)
#define OSTR  218            // out-buf row stride (floats), NO pad (masked writes)
#define NBLK  (32 * OUT_H)   // 6976 = 8 XCDs * 872; 872 ranks = exactly 4 images

typedef short bf16x8 __attribute__((ext_vector_type(8)));
typedef float f32x4  __attribute__((ext_vector_type(4)));

__device__ inline unsigned int f2bf(float f) {   // RNE f32 -> bf16 (proven R5/R6)
    unsigned int u = __builtin_bit_cast(unsigned int, f);
    return (u + 0x7fffu + ((u >> 16) & 1u)) >> 16;
}

// Pack weights into MFMA A-fragments (bf16, 7x7 zero-padded to 8x8). Verified R5/R6.
// [fc = mt*2+kt][lane]: ch = 16*mt + (lane&15), dy = 4*kt + (lane>>4),
// word j = {dx=2j (lo), dx=2j+1 (hi)}.
__global__ __launch_bounds__(512) void repack_w(const float* __restrict__ wgt,
                                                unsigned int* __restrict__ wa) {
    const int t    = threadIdx.x;
    const int lane = t & 63;
    const int fc   = t >> 6;
    const int mt   = fc >> 1, kt = fc & 1;
    const int ch   = 16 * mt + (lane & 15);
    const int dy   = 4 * kt + (lane >> 4);
    unsigned int w[4];
#pragma unroll
    for (int j = 0; j < 4; ++j) {
        float lo = (dy < 7 && 2 * j     < 7) ? wgt[ch * 49 + dy * 7 + 2 * j]     : 0.f;
        float hi = (dy < 7 && 2 * j + 1 < 7) ? wgt[ch * 49 + dy * 7 + 2 * j + 1] : 0.f;
        w[j] = f2bf(lo) | (f2bf(hi) << 16);
    }
    reinterpret_cast<uint4*>(wa)[fc * 64 + lane] = make_uint4(w[0], w[1], w[2], w[3]);
}

// Block = (image n, ONE output row y). Compute all 64ch x 218 cols into LDS,
// then store long sequential runs: wave w writes planes 8w..8w+7, each 872B
// contiguous -> 16 active HBM streams/CU instead of ~450 interleaved 64B ones.
__global__ __launch_bounds__(512) void conv7x7_row(
    const float* __restrict__ in,
    const unsigned int* __restrict__ wa,
    float* __restrict__ out)
{
    __shared__ float tile[8 * TSTR];      //  7424 B: input rows y..y+7 (+zero pad cols)
    __shared__ float obuf[NCH * OSTR];    // 55808 B: one output row, all channels

    const int tid  = threadIdx.x;
    const int lane = tid & 63;
    const int wid  = tid >> 6;
    const int g    = lane >> 4;           // k-group -> dy / channel sub-row
    const int c    = lane & 15;           // pixel-in-group

    // Chunked XCD map (bijective: 6976 = 8*872): XCD k gets 4 whole images.
    const int bid  = blockIdx.x;
    const int rank = (bid & 7) * (NBLK / 8) + (bid >> 3);
    const int n    = rank / OUT_H;
    const int y    = rank - n * OUT_H;

    // ---- stationary A-fragments ----
    union AB { uint4 u; bf16x8 v; };
    AB af[8];
    const uint4* wa4 = reinterpret_cast<const uint4*>(wa);
#pragma unroll
    for (int f = 0; f < 8; ++f) af[f].u = wa4[f * 64 + lane];

    // ---- stage 8 input rows (row y+7 clamped; it only meets zero weights) ----
    const float* inb = in + (size_t)n * (IN_H * IN_W);
    for (int idx = tid; idx < 8 * 116; idx += 512) {
        int r = idx / 116, c2 = idx - r * 116;
        int iny = min(y + r, IN_H - 1);
        float2 v = (c2 < 112) ? *reinterpret_cast<const float2*>(inb + iny * IN_W + 2 * c2)
                              : make_float2(0.f, 0.f);   // zero pad cols 224..231
        tile[r * TSTR + 2 * c2]     = v.x;
        tile[r * TSTR + 2 * c2 + 1] = v.y;
    }
    __syncthreads();

    // ---- compute: 14 x-strips of 16 cols, round-robin over waves ----
    for (int s = wid; s < 14; s += 8) {
        const int x0 = 16 * s;

        AB bf[2];
#pragma unroll
        for (int kt = 0; kt < 2; ++kt) {
            const float* rb = &tile[(4 * kt + g) * TSTR + x0 + c];
            unsigned int b0 = f2bf(rb[0]) | (f2bf(rb[1]) << 16);
            unsigned int b1 = f2bf(rb[2]) | (f2bf(rb[3]) << 16);
            unsigned int b2 = f2bf(rb[4]) | (f2bf(rb[5]) << 16);
            unsigned int b3 = f2bf(rb[6]) | (f2bf(rb[7]) << 16);
            bf[kt].u = make_uint4(b0, b1, b2, b3);
        }

        f32x4 acc[4] = {{0.f,0.f,0.f,0.f},{0.f,0.f,0.f,0.f},
                        {0.f,0.f,0.f,0.f},{0.f,0.f,0.f,0.f}};
#pragma unroll
        for (int mt = 0; mt < 4; ++mt) {
            acc[mt] = __builtin_amdgcn_mfma_f32_16x16x32_bf16(af[mt*2+0].v, bf[0].v, acc[mt], 0, 0, 0);
            acc[mt] = __builtin_amdgcn_mfma_f32_16x16x32_bf16(af[mt*2+1].v, bf[1].v, acc[mt], 0, 0, 0);
        }

        // obuf[ch][col]; MUST mask col>=218 (no row pad -> would corrupt next plane)
        if (x0 + c < OUT_W) {
#pragma unroll
            for (int mt = 0; mt < 4; ++mt)
#pragma unroll
                for (int r = 0; r < 4; ++r)
                    obuf[(16 * mt + 4 * g + r) * OSTR + x0 + c] = acc[mt][r];
        }
    }
    __syncthreads();

    // ---- store: wave w -> planes 8w..8w+7, each one 872B sequential run ----
    const size_t base = (size_t)n * NCH * PLANE + (size_t)y * OUT_W;
#pragma unroll
    for (int i = 0; i < 8; ++i) {
        const int p = 8 * wid + i;
        const float* src = &obuf[p * OSTR];
        float* dst = out + base + (size_t)p * PLANE;
#pragma unroll
        for (int jj = 0; jj < 4; ++jj) {
            int x = 64 * jj + lane;
            if (x < OUT_W) dst[x] = src[x];
        }
    }
}

extern "C" void kernel_launch(void* const* d_in, const int* in_sizes, int n_in,
                              void* d_out, int out_size, void* d_ws, size_t ws_size,
                              hipStream_t stream) {
    const float* in  = (const float*)d_in[0];
    const float* wgt = (const float*)d_in[1];
    float* out = (float*)d_out;
    unsigned int* wa = (unsigned int*)d_ws;   // 8*64*16 = 8192 B

    repack_w<<<1, 512, 0, stream>>>(wgt, wa);
    conv7x7_row<<<NBLK, 512, 0, stream>>>(in, wa, out);
}